// Round 1
// baseline (951.071 us; speedup 1.0000x reference)
//
#include <hip/hip_runtime.h>
#include <hip/hip_bf16.h>

typedef __attribute__((ext_vector_type(8))) __bf16 bf16x8;
typedef __attribute__((ext_vector_type(4))) __bf16 bf16x4;
typedef __attribute__((ext_vector_type(4))) float  f32x4;

#define NB 16
#define NS 2048
#define ND 128
#define QT 64
#define KT 64
#define NKT (NS / KT)
#define SCALE 0.08838834764831845f  // 1/sqrt(128)

// swizzled LDS vector load: rows of 256 B (128 bf16)
__device__ __forceinline__ bf16x8 ld8_256(const __bf16* base, int row, int byteInRow) {
    int off = row * 256 + (byteInRow ^ ((row & 7) << 4));
    return *reinterpret_cast<const bf16x8*>(reinterpret_cast<const char*>(base) + off);
}
// swizzled LDS vector load: rows of 128 B (64 bf16)
__device__ __forceinline__ bf16x8 ld8_128(const __bf16* base, int row, int byteInRow) {
    int off = row * 128 + (byteInRow ^ ((row & 7) << 4));
    return *reinterpret_cast<const bf16x8*>(reinterpret_cast<const char*>(base) + off);
}

// stage 64x128 f32 tile -> bf16 LDS (row-major, XOR-swizzled), 256 threads
__device__ __forceinline__ void stage_rm(__bf16* dst, const float* src, int t) {
    int row = t >> 2, cg = t & 3;
    const float4* s4 = reinterpret_cast<const float4*>(src + (size_t)row * ND) + cg * 8;
    #pragma unroll
    for (int j = 0; j < 8; ++j) {
        float4 f = s4[j];
        bf16x4 h;
        h[0] = (__bf16)f.x; h[1] = (__bf16)f.y; h[2] = (__bf16)f.z; h[3] = (__bf16)f.w;
        int off = (cg * 64 + j * 8) ^ ((row & 7) << 4);
        *reinterpret_cast<bf16x4*>(reinterpret_cast<char*>(dst) + row * 256 + off) = h;
    }
}

__global__ __launch_bounds__(256, 2) void qa_fused(
    const float* __restrict__ qg, const float* __restrict__ kg,
    const float* __restrict__ vg, const int* __restrict__ mg,
    float* __restrict__ outg, float* __restrict__ pg)
{
    __shared__ __bf16 Qs[QT * ND];          // 16 KB, swizzled
    __shared__ __bf16 Ks[KT * ND];          // 16 KB, swizzled
    __shared__ __bf16 Vt[ND * KT];          // 16 KB, transposed+swizzled
    __shared__ __bf16 Ps[4 * 16 * KT];      //  8 KB, per-wave P tile
    __shared__ unsigned int bm[QT][64];     // 16 KB, mask bits for all 2048 k

    const int bid = blockIdx.x;
    // XCD-aware swizzle: 512 wgs, 8 XCDs -> each XCD owns 2 consecutive batches
    const int lb  = (bid & 7) * 64 + (bid >> 3);
    const int b   = lb >> 5;
    const int q0  = (lb & 31) * QT;
    const int t   = threadIdx.x;
    const int w   = t >> 6;     // wave 0..3 -> q rows [16w,16w+16)
    const int l   = t & 63;
    const int l15 = l & 15;
    const int g   = l >> 4;     // quarter-wave group

    stage_rm(Qs, qg + ((size_t)b * NS + q0) * ND, t);

    // sink column p[:, :, 0] = 0 (score -1e9 -> exp underflows to 0)
    if (t < QT) pg[((size_t)b * NS + q0 + t) * (size_t)(NS + 1)] = 0.0f;

    __syncthreads();

    // Q fragments live in registers for the whole kernel
    bf16x8 qf[4];
    const int arow = w * 16 + l15;
    #pragma unroll
    for (int kc = 0; kc < 4; ++kc) qf[kc] = ld8_256(Qs, arow, kc * 64 + g * 16);

    float mrun[4], srun[4];
    #pragma unroll
    for (int r = 0; r < 4; ++r) { mrun[r] = -1e9f; srun[r] = 0.0f; }

    // ---------------- Sweep A: online (max, sum-exp) + bitmask pack ----------------
    for (int kt = 0; kt < NKT; ++kt) {
        const int k0 = kt * KT;
        __syncthreads();
        stage_rm(Ks, kg + ((size_t)b * NS + k0) * ND, t);
        // mask -> ballot bits; wave w handles its own 16 rows (wave-local LDS use)
        #pragma unroll 4
        for (int i = 0; i < 16; ++i) {
            int row = w * 16 + i;
            int mv = mg[((size_t)b * NS + (q0 + row)) * NS + k0 + l];
            unsigned long long bal = __ballot(mv != 0);
            if (l == 0) {
                bm[row][2 * kt]     = (unsigned)bal;
                bm[row][2 * kt + 1] = (unsigned)(bal >> 32);
            }
        }
        __syncthreads();

        f32x4 acc[4];
        #pragma unroll
        for (int c = 0; c < 4; ++c) {
            f32x4 z = {0.f, 0.f, 0.f, 0.f};
            acc[c] = z;
            #pragma unroll
            for (int kc = 0; kc < 4; ++kc) {
                bf16x8 bf = ld8_256(Ks, c * 16 + l15, kc * 64 + g * 16);
                acc[c] = __builtin_amdgcn_mfma_f32_16x16x32_bf16(qf[kc], bf, acc[c], 0, 0, 0);
            }
        }

        #pragma unroll
        for (int r = 0; r < 4; ++r) {
            const int row = w * 16 + g * 4 + r;
            const unsigned w0 = bm[row][2 * kt], w1 = bm[row][2 * kt + 1];
            float sv[4], tmax = -1e9f;
            #pragma unroll
            for (int c = 0; c < 4; ++c) {
                int cb = c * 16 + l15;
                unsigned word = (c < 2) ? w0 : w1;
                bool on = (word >> (cb & 31)) & 1u;
                float s = on ? acc[c][r] * SCALE : -1e9f;
                sv[c] = s;
                tmax = fmaxf(tmax, s);
            }
            #pragma unroll
            for (int d = 1; d < 16; d <<= 1) tmax = fmaxf(tmax, __shfl_xor(tmax, d));
            float mnew = fmaxf(mrun[r], tmax);
            float corr = __expf(mrun[r] - mnew);
            float ps = 0.f;
            #pragma unroll
            for (int c = 0; c < 4; ++c) ps += __expf(sv[c] - mnew);
            #pragma unroll
            for (int d = 1; d < 16; d <<= 1) ps += __shfl_xor(ps, d);
            srun[r] = srun[r] * corr + ps;
            mrun[r] = mnew;
        }
    }

    float inv[4];
    #pragma unroll
    for (int r = 0; r < 4; ++r) inv[r] = 1.0f / (1.0f + srun[r]);

    // ---------------- Sweep B: recompute scores, write p, accumulate PV ----------------
    f32x4 oacc[8];
    #pragma unroll
    for (int cf = 0; cf < 8; ++cf) { f32x4 z = {0.f,0.f,0.f,0.f}; oacc[cf] = z; }

    __bf16* Psw = Ps + w * (16 * KT);

    for (int kt = 0; kt < NKT; ++kt) {
        const int k0 = kt * KT;
        __syncthreads();
        stage_rm(Ks, kg + ((size_t)b * NS + k0) * ND, t);
        {   // stage V transposed: Vt[d][k]
            int kk = t >> 2, dg = t & 3;
            const float4* s4 = reinterpret_cast<const float4*>(vg + ((size_t)b * NS + k0 + kk) * ND) + dg * 8;
            #pragma unroll
            for (int j = 0; j < 8; ++j) {
                float4 f = s4[j];
                int d0 = dg * 32 + j * 4;
                float fv[4] = {f.x, f.y, f.z, f.w};
                #pragma unroll
                for (int e = 0; e < 4; ++e) {
                    int d = d0 + e;
                    int off = d * 128 + ((kk * 2) ^ ((d & 7) << 4));
                    *reinterpret_cast<__bf16*>(reinterpret_cast<char*>(Vt) + off) = (__bf16)fv[e];
                }
            }
        }
        __syncthreads();

        f32x4 acc[4];
        #pragma unroll
        for (int c = 0; c < 4; ++c) {
            f32x4 z = {0.f, 0.f, 0.f, 0.f};
            acc[c] = z;
            #pragma unroll
            for (int kc = 0; kc < 4; ++kc) {
                bf16x8 bf = ld8_256(Ks, c * 16 + l15, kc * 64 + g * 16);
                acc[c] = __builtin_amdgcn_mfma_f32_16x16x32_bf16(qf[kc], bf, acc[c], 0, 0, 0);
            }
        }

        // p = exp(s - m)/denom (0 if masked); write f32 to global, bf16 to LDS
        #pragma unroll
        for (int r = 0; r < 4; ++r) {
            const int row16 = g * 4 + r;
            const int row = w * 16 + row16;
            const unsigned w0 = bm[row][2 * kt], w1 = bm[row][2 * kt + 1];
            const size_t prow = ((size_t)b * NS + q0 + row) * (size_t)(NS + 1);
            #pragma unroll
            for (int c = 0; c < 4; ++c) {
                int cb = c * 16 + l15;
                unsigned word = (c < 2) ? w0 : w1;
                bool on = (word >> (cb & 31)) & 1u;
                float p = on ? __expf(acc[c][r] * SCALE - mrun[r]) * inv[r] : 0.0f;
                pg[prow + 1 + k0 + cb] = p;
                int off = row16 * 128 + ((cb * 2) ^ ((row16 & 7) << 4));
                *reinterpret_cast<__bf16*>(reinterpret_cast<char*>(Psw) + off) = (__bf16)p;
            }
        }

        // PV: out_tile += P(16x64) * V(64x128); Ps is wave-local (HW orders same-wave DS ops)
        #pragma unroll
        for (int kc = 0; kc < 2; ++kc) {
            bf16x8 af = ld8_128(Psw, l15, kc * 64 + g * 16);
            #pragma unroll
            for (int cf = 0; cf < 8; ++cf) {
                bf16x8 vf = ld8_128(Vt, cf * 16 + l15, kc * 64 + g * 16);
                oacc[cf] = __builtin_amdgcn_mfma_f32_16x16x32_bf16(af, vf, oacc[cf], 0, 0, 0);
            }
        }
    }

    #pragma unroll
    for (int cf = 0; cf < 8; ++cf) {
        #pragma unroll
        for (int r = 0; r < 4; ++r) {
            outg[((size_t)b * NS + q0 + w * 16 + g * 4 + r) * ND + cf * 16 + l15] = oacc[cf][r];
        }
    }
}

extern "C" void kernel_launch(void* const* d_in, const int* in_sizes, int n_in,
                              void* d_out, int out_size, void* d_ws, size_t ws_size,
                              hipStream_t stream) {
    const float* q = (const float*)d_in[0];
    const float* k = (const float*)d_in[1];
    const float* v = (const float*)d_in[2];
    const int*  mk = (const int*)d_in[3];
    float* out = (float*)d_out;
    float* p   = out + (size_t)NB * NS * ND;   // p_attn follows out
    dim3 grid(NB * (NS / QT));  // 512
    dim3 block(256);
    qa_fused<<<grid, block, 0, stream>>>(q, k, v, mk, out, p);
}

// Round 2
// 665.269 us; speedup vs baseline: 1.4296x; 1.4296x over previous
//
#include <hip/hip_runtime.h>
#include <hip/hip_bf16.h>

typedef __attribute__((ext_vector_type(8))) __bf16 bf16x8;
typedef __attribute__((ext_vector_type(4))) __bf16 bf16x4;
typedef __attribute__((ext_vector_type(4))) float  f32x4;
typedef float f32x4u __attribute__((ext_vector_type(4), aligned(4)));

#define NB 16
#define NS 2048
#define ND 128
#define QT 64
#define KT 64
#define NKT (NS / KT)
#define SCALE 0.08838834764831845f  // 1/sqrt(128)

// ---------------- shared helpers ----------------
__device__ __forceinline__ bf16x8 ld8_256(const __bf16* base, int row, int byteInRow) {
    int off = row * 256 + (byteInRow ^ ((row & 7) << 4));
    return *reinterpret_cast<const bf16x8*>(reinterpret_cast<const char*>(base) + off);
}
__device__ __forceinline__ bf16x8 ld8_128(const __bf16* base, int row, int byteInRow) {
    int off = row * 128 + (byteInRow ^ ((row & 7) << 4));
    return *reinterpret_cast<const bf16x8*>(reinterpret_cast<const char*>(base) + off);
}
__device__ __forceinline__ void glds16(const void* g, void* l) {
    __builtin_amdgcn_global_load_lds(
        (const __attribute__((address_space(1))) unsigned int*)g,
        (__attribute__((address_space(3))) unsigned int*)l, 16, 0, 0);
}

// ---------------- preconversion kernels ----------------
// q,k f32 -> bf16 (q pre-scaled by 1/sqrt(d))
__global__ __launch_bounds__(256) void conv_qk(const float* __restrict__ q,
                                               const float* __restrict__ k,
                                               __bf16* __restrict__ qb,
                                               __bf16* __restrict__ kb) {
    size_t i = (size_t)blockIdx.x * 256 + threadIdx.x;       // chunk of 8 elems
    const float4* qs = (const float4*)q;
    const float4* ks = (const float4*)k;
    float4 a = qs[2 * i], b = qs[2 * i + 1];
    bf16x8 o;
    o[0] = (__bf16)(a.x * SCALE); o[1] = (__bf16)(a.y * SCALE);
    o[2] = (__bf16)(a.z * SCALE); o[3] = (__bf16)(a.w * SCALE);
    o[4] = (__bf16)(b.x * SCALE); o[5] = (__bf16)(b.y * SCALE);
    o[6] = (__bf16)(b.z * SCALE); o[7] = (__bf16)(b.w * SCALE);
    *(bf16x8*)&qb[i * 8] = o;
    a = ks[2 * i]; b = ks[2 * i + 1];
    o[0] = (__bf16)a.x; o[1] = (__bf16)a.y; o[2] = (__bf16)a.z; o[3] = (__bf16)a.w;
    o[4] = (__bf16)b.x; o[5] = (__bf16)b.y; o[6] = (__bf16)b.z; o[7] = (__bf16)b.w;
    *(bf16x8*)&kb[i * 8] = o;
}

// v f32 [b][s][d] -> bf16 transposed [b][d][s]
__global__ __launch_bounds__(256) void conv_vt(const float* __restrict__ v,
                                               __bf16* __restrict__ vt) {
    int b = blockIdx.x >> 4, st = blockIdx.x & 15;
    int s0 = st * 128, t = threadIdx.x;
    #pragma unroll
    for (int i = 0; i < 8; ++i) {
        int task = i * 256 + t;
        int d = task & 127, sg = task >> 7;                  // sg in [0,16)
        bf16x8 o;
        #pragma unroll
        for (int j = 0; j < 8; ++j)
            o[j] = (__bf16)v[((size_t)b * NS + s0 + sg * 8 + j) * ND + d];
        *(bf16x8*)&vt[((size_t)b * ND + d) * NS + s0 + sg * 8] = o;
    }
}

// ---------------- main fused kernel ----------------
__global__ __launch_bounds__(256, 2) void qa_main(
    const __bf16* __restrict__ qb, const __bf16* __restrict__ kb,
    const __bf16* __restrict__ vtb, const int* __restrict__ mg,
    float* __restrict__ outg, float* __restrict__ pg)
{
    __shared__ __align__(16) char bufs[3][KT * ND * 2];     // 3 x 16 KB K/V tiles
    __shared__ unsigned int bm[QT * 68];                    // 17 KB packed mask
    __shared__ __align__(16) __bf16 Ps[4][16 * KT];         // 8 KB per-wave P

    const int bid = blockIdx.x;
    const int lb  = (bid & 7) * 64 + (bid >> 3);            // XCD swizzle (512 wgs)
    const int b   = lb >> 5;
    const int q0  = (lb & 31) * QT;
    const int t   = threadIdx.x;
    const int w   = t >> 6;
    const int l   = t & 63;
    const int l15 = l & 15;
    const int g   = l >> 4;

    const __bf16* kbB  = kb  + (size_t)b * NS * ND;
    const __bf16* vtbB = vtb + (size_t)b * ND * NS;

    // ---- mask pack: bm[row][chunk8][hi2][e4]; bit l of ballot e = col chunk*256+4l+e
    #pragma unroll 2
    for (int i = 0; i < 32; ++i) {                          // wave: 16 rows x 8 chunks / 4 sub?
        int task = i * 2 + (l >> 5);                        // 64 tasks per wave? no: see below
        (void)task;
        break;
    }
    // 128 whole-wave iterations per wave: row in wave's 16 rows, 8 chunks each
    for (int i = 0; i < 128; ++i) {
        int row = w * 16 + (i >> 3), chunk = i & 7;
        const int4* mp = (const int4*)(mg + (size_t)(b * NS + q0 + row) * NS + chunk * 256) + l;
        int4 mv = *mp;
        unsigned long long b0 = __ballot(mv.x != 0);
        unsigned long long b1 = __ballot(mv.y != 0);
        unsigned long long b2 = __ballot(mv.z != 0);
        unsigned long long b3 = __ballot(mv.w != 0);
        if (l == 0) {
            uint4 lo = { (unsigned)b0, (unsigned)b1, (unsigned)b2, (unsigned)b3 };
            uint4 hi = { (unsigned)(b0 >> 32), (unsigned)(b1 >> 32),
                         (unsigned)(b2 >> 32), (unsigned)(b3 >> 32) };
            *(uint4*)&bm[row * 68 + chunk * 8]     = lo;
            *(uint4*)&bm[row * 68 + chunk * 8 + 4] = hi;
        }
    }

    if (t < QT) pg[(size_t)(b * NS + q0 + t) * (size_t)(NS + 1)] = 0.0f;  // sink col

    // Q fragments (second operand): lane holds Q row (w*16+l15), d-elems g*8..
    bf16x8 qf[4];
    {
        const __bf16* qrow = qb + (size_t)(b * NS + q0 + w * 16 + l15) * ND;
        #pragma unroll
        for (int kc = 0; kc < 4; ++kc)
            qf[kc] = *(const bf16x8*)(qrow + kc * 32 + g * 8);
    }

    // ---- K tile stage (pre-swizzled source, linear LDS dest) ----
    auto stageK = [&](char* buf, int k0) {
        #pragma unroll
        for (int i = 0; i < 4; ++i) {
            int c = i * 256 + t;
            int row = c >> 4, pc = c & 15, lc = pc ^ (row & 7);
            glds16(kbB + (size_t)(k0 + row) * ND + lc * 8, buf + c * 16);
        }
    };
    auto stageV = [&](char* buf, int k0) {
        #pragma unroll
        for (int i = 0; i < 4; ++i) {
            int c = i * 256 + t;
            int d = c >> 3, pc = c & 7, lc = pc ^ (d & 7);
            glds16(vtbB + (size_t)d * NS + k0 + lc * 8, buf + c * 16);
        }
    };

    stageK(bufs[0], 0);
    __syncthreads();   // mask pack + Q + K0 ready

    const int myrow = w * 16 + l15;
    float mrun = -1e9f, srun = 0.0f;

    // ================= Sweep A: exact row max + sum =================
    for (int kt = 0; kt < NKT; ++kt) {
        const int k0 = kt * KT;
        if (kt + 1 < NKT) stageK(bufs[(kt + 1) & 1], k0 + KT);
        const __bf16* Kbuf = (const __bf16*)bufs[kt & 1];

        f32x4 acc[4];
        #pragma unroll
        for (int c = 0; c < 4; ++c) {
            f32x4 z = {0.f, 0.f, 0.f, 0.f}; acc[c] = z;
            #pragma unroll
            for (int kc = 0; kc < 4; ++kc) {
                bf16x8 kf = ld8_256(Kbuf, c * 16 + l15, kc * 64 + g * 16);
                acc[c] = __builtin_amdgcn_mfma_f32_16x16x32_bf16(kf, qf[kc], acc[c], 0, 0, 0);
            }
        }

        uint4 W = *(const uint4*)&bm[myrow * 68 + (k0 >> 8) * 8 + ((k0 & 128) >> 5)];
        unsigned Wr[4] = { W.x, W.y, W.z, W.w };
        const int sh = ((k0 & 64) >> 2) + g;

        float sv[16], tmax = -1e30f;
        #pragma unroll
        for (int c = 0; c < 4; ++c)
            #pragma unroll
            for (int r = 0; r < 4; ++r) {
                float s = ((Wr[r] >> (sh + c * 4)) & 1u) ? acc[c][r] : -1e30f;
                sv[c * 4 + r] = s;
                tmax = fmaxf(tmax, s);
            }
        tmax = fmaxf(tmax, __shfl_xor(tmax, 16));
        tmax = fmaxf(tmax, __shfl_xor(tmax, 32));
        float mnew = fmaxf(mrun, tmax);
        float corr = __expf(mrun - mnew);
        float ps = 0.f;
        #pragma unroll
        for (int i = 0; i < 16; ++i) ps += __expf(sv[i] - mnew);
        ps += __shfl_xor(ps, 16);
        ps += __shfl_xor(ps, 32);
        srun = srun * corr + ps;
        mrun = mnew;
        __syncthreads();
    }

    const float inv = 1.0f / (1.0f + srun);

    // ================= Sweep B: p write + PV =================
    f32x4 oacc[8];
    #pragma unroll
    for (int cf = 0; cf < 8; ++cf) { f32x4 z = {0.f,0.f,0.f,0.f}; oacc[cf] = z; }

    stageK(bufs[0], 0);
    stageV(bufs[1], 0);
    __syncthreads();

    int iA = 0, iB = 1, iC = 2;
    const size_t prow = (size_t)(b * NS + q0 + myrow) * (size_t)(NS + 1);
    __bf16* Psw = Ps[w];

    for (int kt = 0; kt < NKT; ++kt) {
        const int k0 = kt * KT;
        if (kt + 1 < NKT) stageK(bufs[iC], k0 + KT);
        const __bf16* Kbuf = (const __bf16*)bufs[iA];

        f32x4 acc[4];
        #pragma unroll
        for (int c = 0; c < 4; ++c) {
            f32x4 z = {0.f, 0.f, 0.f, 0.f}; acc[c] = z;
            #pragma unroll
            for (int kc = 0; kc < 4; ++kc) {
                bf16x8 kf = ld8_256(Kbuf, c * 16 + l15, kc * 64 + g * 16);
                acc[c] = __builtin_amdgcn_mfma_f32_16x16x32_bf16(kf, qf[kc], acc[c], 0, 0, 0);
            }
        }

        uint4 W = *(const uint4*)&bm[myrow * 68 + (k0 >> 8) * 8 + ((k0 & 128) >> 5)];
        unsigned Wr[4] = { W.x, W.y, W.z, W.w };
        const int sh = ((k0 & 64) >> 2) + g;

        #pragma unroll
        for (int c = 0; c < 4; ++c) {
            f32x4 pv;
            bf16x4 pb;
            #pragma unroll
            for (int r = 0; r < 4; ++r) {
                bool on = (Wr[r] >> (sh + c * 4)) & 1u;
                float p = on ? __expf(acc[c][r] - mrun) * inv : 0.0f;
                pv[r] = p;
                pb[r] = (__bf16)p;
            }
            *(f32x4u*)&pg[prow + 1 + k0 + c * 16 + g * 4] = pv;
            int off = l15 * 128 + ((c * 32 + g * 8) ^ ((l15 & 7) << 4));
            *(bf16x4*)((char*)Psw + off) = pb;
        }

        __syncthreads();                       // QK^T readers done with bufs[iA]
        if (kt + 1 < NKT) stageV(bufs[iA], k0 + KT);
        const __bf16* Vbuf = (const __bf16*)bufs[iB];

        #pragma unroll
        for (int kc = 0; kc < 2; ++kc) {
            bf16x8 af = ld8_128(Psw, l15, kc * 64 + g * 16);
            #pragma unroll
            for (int cf = 0; cf < 8; ++cf) {
                bf16x8 vf = ld8_128(Vbuf, cf * 16 + l15, kc * 64 + g * 16);
                oacc[cf] = __builtin_amdgcn_mfma_f32_16x16x32_bf16(af, vf, oacc[cf], 0, 0, 0);
            }
        }
        __syncthreads();                       // V(kt+1) landed; bufs[iB] free
        int tmp = iA; iA = iC; iC = iB; iB = tmp;
    }

    #pragma unroll
    for (int cf = 0; cf < 8; ++cf)
        #pragma unroll
        for (int r = 0; r < 4; ++r)
            outg[(size_t)(b * NS + q0 + w * 16 + g * 4 + r) * ND + cf * 16 + l15] = oacc[cf][r];
}

// ---------------- round-1 fallback (used only if ws too small) ----------------
__device__ __forceinline__ void stage_rm(__bf16* dst, const float* src, int t) {
    int row = t >> 2, cg = t & 3;
    const float4* s4 = reinterpret_cast<const float4*>(src + (size_t)row * ND) + cg * 8;
    #pragma unroll
    for (int j = 0; j < 8; ++j) {
        float4 f = s4[j];
        bf16x4 h;
        h[0] = (__bf16)f.x; h[1] = (__bf16)f.y; h[2] = (__bf16)f.z; h[3] = (__bf16)f.w;
        int off = (cg * 64 + j * 8) ^ ((row & 7) << 4);
        *reinterpret_cast<bf16x4*>(reinterpret_cast<char*>(dst) + row * 256 + off) = h;
    }
}

__global__ __launch_bounds__(256, 2) void qa_fused_fb(
    const float* __restrict__ qg, const float* __restrict__ kg,
    const float* __restrict__ vg, const int* __restrict__ mg,
    float* __restrict__ outg, float* __restrict__ pg)
{
    __shared__ __bf16 Qs[QT * ND];
    __shared__ __bf16 Ks[KT * ND];
    __shared__ __bf16 Vt[ND * KT];
    __shared__ __bf16 Psf[4 * 16 * KT];
    __shared__ unsigned int bmf[QT][64];

    const int bid = blockIdx.x;
    const int lb  = (bid & 7) * 64 + (bid >> 3);
    const int b   = lb >> 5;
    const int q0  = (lb & 31) * QT;
    const int t   = threadIdx.x;
    const int w   = t >> 6;
    const int l   = t & 63;
    const int l15 = l & 15;
    const int g   = l >> 4;

    stage_rm(Qs, qg + ((size_t)b * NS + q0) * ND, t);
    if (t < QT) pg[((size_t)b * NS + q0 + t) * (size_t)(NS + 1)] = 0.0f;
    __syncthreads();

    bf16x8 qf[4];
    const int arow = w * 16 + l15;
    #pragma unroll
    for (int kc = 0; kc < 4; ++kc) qf[kc] = ld8_256(Qs, arow, kc * 64 + g * 16);

    float mrun[4], srun[4];
    #pragma unroll
    for (int r = 0; r < 4; ++r) { mrun[r] = -1e9f; srun[r] = 0.0f; }

    for (int kt = 0; kt < NKT; ++kt) {
        const int k0 = kt * KT;
        __syncthreads();
        stage_rm(Ks, kg + ((size_t)b * NS + k0) * ND, t);
        #pragma unroll 4
        for (int i = 0; i < 16; ++i) {
            int row = w * 16 + i;
            int mv = mg[((size_t)b * NS + (q0 + row)) * NS + k0 + l];
            unsigned long long bal = __ballot(mv != 0);
            if (l == 0) {
                bmf[row][2 * kt]     = (unsigned)bal;
                bmf[row][2 * kt + 1] = (unsigned)(bal >> 32);
            }
        }
        __syncthreads();

        f32x4 acc[4];
        #pragma unroll
        for (int c = 0; c < 4; ++c) {
            f32x4 z = {0.f, 0.f, 0.f, 0.f};
            acc[c] = z;
            #pragma unroll
            for (int kc = 0; kc < 4; ++kc) {
                bf16x8 bf = ld8_256(Ks, c * 16 + l15, kc * 64 + g * 16);
                acc[c] = __builtin_amdgcn_mfma_f32_16x16x32_bf16(qf[kc], bf, acc[c], 0, 0, 0);
            }
        }

        #pragma unroll
        for (int r = 0; r < 4; ++r) {
            const int row = w * 16 + g * 4 + r;
            const unsigned w0 = bmf[row][2 * kt], w1 = bmf[row][2 * kt + 1];
            float sv[4], tmax = -1e9f;
            #pragma unroll
            for (int c = 0; c < 4; ++c) {
                int cb = c * 16 + l15;
                unsigned word = (c < 2) ? w0 : w1;
                bool on = (word >> (cb & 31)) & 1u;
                float s = on ? acc[c][r] * SCALE : -1e9f;
                sv[c] = s;
                tmax = fmaxf(tmax, s);
            }
            #pragma unroll
            for (int d = 1; d < 16; d <<= 1) tmax = fmaxf(tmax, __shfl_xor(tmax, d));
            float mnew = fmaxf(mrun[r], tmax);
            float corr = __expf(mrun[r] - mnew);
            float ps = 0.f;
            #pragma unroll
            for (int c = 0; c < 4; ++c) ps += __expf(sv[c] - mnew);
            #pragma unroll
            for (int d = 1; d < 16; d <<= 1) ps += __shfl_xor(ps, d);
            srun[r] = srun[r] * corr + ps;
            mrun[r] = mnew;
        }
    }

    float inv[4];
    #pragma unroll
    for (int r = 0; r < 4; ++r) inv[r] = 1.0f / (1.0f + srun[r]);

    f32x4 oacc[8];
    #pragma unroll
    for (int cf = 0; cf < 8; ++cf) { f32x4 z = {0.f,0.f,0.f,0.f}; oacc[cf] = z; }

    __bf16* Psw = Psf + w * (16 * KT);

    for (int kt = 0; kt < NKT; ++kt) {
        const int k0 = kt * KT;
        __syncthreads();
        stage_rm(Ks, kg + ((size_t)b * NS + k0) * ND, t);
        {
            int kk = t >> 2, dg = t & 3;
            const float4* s4 = reinterpret_cast<const float4*>(vg + ((size_t)b * NS + k0 + kk) * ND) + dg * 8;
            #pragma unroll
            for (int j = 0; j < 8; ++j) {
                float4 f = s4[j];
                int d0 = dg * 32 + j * 4;
                float fv[4] = {f.x, f.y, f.z, f.w};
                #pragma unroll
                for (int e = 0; e < 4; ++e) {
                    int d = d0 + e;
                    int off = d * 128 + ((kk * 2) ^ ((d & 7) << 4));
                    *reinterpret_cast<__bf16*>(reinterpret_cast<char*>(Vt) + off) = (__bf16)fv[e];
                }
            }
        }
        __syncthreads();

        f32x4 acc[4];
        #pragma unroll
        for (int c = 0; c < 4; ++c) {
            f32x4 z = {0.f, 0.f, 0.f, 0.f};
            acc[c] = z;
            #pragma unroll
            for (int kc = 0; kc < 4; ++kc) {
                bf16x8 bf = ld8_256(Ks, c * 16 + l15, kc * 64 + g * 16);
                acc[c] = __builtin_amdgcn_mfma_f32_16x16x32_bf16(qf[kc], bf, acc[c], 0, 0, 0);
            }
        }

        #pragma unroll
        for (int r = 0; r < 4; ++r) {
            const int row16 = g * 4 + r;
            const int row = w * 16 + row16;
            const unsigned w0 = bmf[row][2 * kt], w1 = bmf[row][2 * kt + 1];
            const size_t prow = ((size_t)b * NS + q0 + row) * (size_t)(NS + 1);
            #pragma unroll
            for (int c = 0; c < 4; ++c) {
                int cb = c * 16 + l15;
                unsigned word = (c < 2) ? w0 : w1;
                bool on = (word >> (cb & 31)) & 1u;
                float p = on ? __expf(acc[c][r] * SCALE - mrun[r]) * inv[r] : 0.0f;
                pg[prow + 1 + k0 + cb] = p;
                int off = row16 * 128 + ((cb * 2) ^ ((row16 & 7) << 4));
                *reinterpret_cast<__bf16*>(reinterpret_cast<char*>(Psw) + off) = (__bf16)p;
            }
        }

        #pragma unroll
        for (int kc = 0; kc < 2; ++kc) {
            bf16x8 af = ld8_128(Psw, l15, kc * 64 + g * 16);
            #pragma unroll
            for (int cf = 0; cf < 8; ++cf) {
                bf16x8 vf = ld8_128(Vt, cf * 16 + l15, kc * 64 + g * 16);
                oacc[cf] = __builtin_amdgcn_mfma_f32_16x16x32_bf16(af, vf, oacc[cf], 0, 0, 0);
            }
        }
    }

    #pragma unroll
    for (int cf = 0; cf < 8; ++cf)
        #pragma unroll
        for (int r = 0; r < 4; ++r)
            outg[((size_t)b * NS + q0 + w * 16 + g * 4 + r) * ND + cf * 16 + l15] = oacc[cf][r];
}

extern "C" void kernel_launch(void* const* d_in, const int* in_sizes, int n_in,
                              void* d_out, int out_size, void* d_ws, size_t ws_size,
                              hipStream_t stream) {
    const float* q = (const float*)d_in[0];
    const float* k = (const float*)d_in[1];
    const float* v = (const float*)d_in[2];
    const int*  mk = (const int*)d_in[3];
    float* out = (float*)d_out;
    float* p   = out + (size_t)NB * NS * ND;

    const size_t elems = (size_t)NB * NS * ND;          // 4,194,304
    const size_t need  = elems * 2 * 3;                 // 3 bf16 arrays ~25.2 MB

    if (ws_size >= need) {
        __bf16* qb = (__bf16*)d_ws;
        __bf16* kb = qb + elems;
        __bf16* vt = kb + elems;
        conv_qk<<<dim3((unsigned)(elems / 8 / 256)), dim3(256), 0, stream>>>(q, k, qb, kb);
        conv_vt<<<dim3(NB * 16), dim3(256), 0, stream>>>(v, vt);
        qa_main<<<dim3(NB * (NS / QT)), dim3(256), 0, stream>>>(qb, kb, vt, mk, out, p);
    } else {
        qa_fused_fb<<<dim3(NB * (NS / QT)), dim3(256), 0, stream>>>(q, k, v, mk, out, p);
    }
}